// Round 5
// baseline (179.260 us; speedup 1.0000x reference)
//
#include <hip/hip_runtime.h>
#include <hip/hip_bf16.h>

typedef __attribute__((ext_vector_type(4))) float f32x4;
typedef __attribute__((ext_vector_type(8))) short short8v;
typedef __attribute__((ext_vector_type(4))) unsigned short ushort4v;

#define T_ROWS 16384
#define H_DIM  4096
#define E_NUM  64
#define TOPK   8
#define KSPLIT 4
#define KPW    (H_DIM / KSPLIT)   // 1024 k per wave
#define NKSW   (KPW / 32)         // 32 k-steps per wave

__device__ __forceinline__ unsigned short f2bf(float f) {
    unsigned int u = __float_as_uint(f);
    unsigned int r = (u + 0x7fffu + ((u >> 16) & 1u)) >> 16;  // RNE
    return (unsigned short)r;
}
__device__ __forceinline__ float bf2f(unsigned short h) {
    return __uint_as_float(((unsigned int)h) << 16);
}

// ---- prep: split W f32 [64][4096] into bf16 hi/lo planes in d_ws ----
__global__ __launch_bounds__(256) void prep_w(
    const float* __restrict__ W, unsigned short* __restrict__ WH,
    unsigned short* __restrict__ WL)
{
    const int i = (blockIdx.x * 256 + threadIdx.x) * 4;
    const float4 v = *(const float4*)(W + i);
    float f[4] = {v.x, v.y, v.z, v.w};
    ushort4v h, l;
#pragma unroll
    for (int j = 0; j < 4; ++j) {
        unsigned short hb = f2bf(f[j]);
        h[j] = hb;
        l[j] = f2bf(f[j] - bf2f(hb));
    }
    *(ushort4v*)(WH + i) = h;
    *(ushort4v*)(WL + i) = l;
}

// ---- main: block = 4 waves x same 16 rows, K split 4 ways, 1 barrier ----
__global__ __launch_bounds__(256, 4) void router_main(
    const float* __restrict__ X, const unsigned short* __restrict__ WH,
    const unsigned short* __restrict__ WL, const int* __restrict__ ids,
    int nids, float* __restrict__ out)
{
    const int tid  = threadIdx.x;
    const int lane = tid & 63;
    const int wv   = tid >> 6;           // k-split slice
    const int rb   = blockIdx.x * 16;
    const int fr   = lane & 15;
    const int fq   = lane >> 4;
    const int kb   = wv * KPW;

    const float*          xp  = X  + (size_t)(rb + fr) * H_DIM + kb + fq * 8;
    const unsigned short* wh0 = WH + (size_t)fr * H_DIM + kb + fq * 8;
    const unsigned short* wl0 = WL + (size_t)fr * H_DIM + kb + fq * 8;

    f32x4 acc0 = {0.f,0.f,0.f,0.f};
    f32x4 acc1 = acc0, acc2 = acc0, acc3 = acc0;

    // depth-1 register double-buffer for X and B
    float4  pa = *(const float4*)(xp);
    float4  pb = *(const float4*)(xp + 4);
    short8v bh0 = *(const short8v*)(wh0 +  0 * H_DIM);
    short8v bh1 = *(const short8v*)(wh0 + 16 * H_DIM);
    short8v bh2 = *(const short8v*)(wh0 + 32 * H_DIM);
    short8v bh3 = *(const short8v*)(wh0 + 48 * H_DIM);
    short8v bl0 = *(const short8v*)(wl0 +  0 * H_DIM);
    short8v bl1 = *(const short8v*)(wl0 + 16 * H_DIM);
    short8v bl2 = *(const short8v*)(wl0 + 32 * H_DIM);
    short8v bl3 = *(const short8v*)(wl0 + 48 * H_DIM);

    for (int ks = 0; ks < NKSW; ++ks) {
        const int kn = (ks + 1 < NKSW) ? (ks + 1) * 32 : ks * 32;  // clamped next
        const float4  na  = *(const float4*)(xp + kn);
        const float4  nb  = *(const float4*)(xp + kn + 4);
        const short8v nh0 = *(const short8v*)(wh0 +  0 * H_DIM + kn);
        const short8v nh1 = *(const short8v*)(wh0 + 16 * H_DIM + kn);
        const short8v nh2 = *(const short8v*)(wh0 + 32 * H_DIM + kn);
        const short8v nh3 = *(const short8v*)(wh0 + 48 * H_DIM + kn);
        const short8v nl0 = *(const short8v*)(wl0 +  0 * H_DIM + kn);
        const short8v nl1 = *(const short8v*)(wl0 + 16 * H_DIM + kn);
        const short8v nl2 = *(const short8v*)(wl0 + 32 * H_DIM + kn);
        const short8v nl3 = *(const short8v*)(wl0 + 48 * H_DIM + kn);

        // split current X 8 f32 -> bf16 hi/lo
        float v[8] = {pa.x, pa.y, pa.z, pa.w, pb.x, pb.y, pb.z, pb.w};
        short8v ah, al;
#pragma unroll
        for (int j = 0; j < 8; ++j) {
            unsigned short hb = f2bf(v[j]);
            ah[j] = (short)hb;
            al[j] = (short)f2bf(v[j] - bf2f(hb));
        }
        acc0 = __builtin_amdgcn_mfma_f32_16x16x32_bf16(ah, bh0, acc0, 0, 0, 0);
        acc0 = __builtin_amdgcn_mfma_f32_16x16x32_bf16(ah, bl0, acc0, 0, 0, 0);
        acc0 = __builtin_amdgcn_mfma_f32_16x16x32_bf16(al, bh0, acc0, 0, 0, 0);
        acc1 = __builtin_amdgcn_mfma_f32_16x16x32_bf16(ah, bh1, acc1, 0, 0, 0);
        acc1 = __builtin_amdgcn_mfma_f32_16x16x32_bf16(ah, bl1, acc1, 0, 0, 0);
        acc1 = __builtin_amdgcn_mfma_f32_16x16x32_bf16(al, bh1, acc1, 0, 0, 0);
        acc2 = __builtin_amdgcn_mfma_f32_16x16x32_bf16(ah, bh2, acc2, 0, 0, 0);
        acc2 = __builtin_amdgcn_mfma_f32_16x16x32_bf16(ah, bl2, acc2, 0, 0, 0);
        acc2 = __builtin_amdgcn_mfma_f32_16x16x32_bf16(al, bh2, acc2, 0, 0, 0);
        acc3 = __builtin_amdgcn_mfma_f32_16x16x32_bf16(ah, bh3, acc3, 0, 0, 0);
        acc3 = __builtin_amdgcn_mfma_f32_16x16x32_bf16(ah, bl3, acc3, 0, 0, 0);
        acc3 = __builtin_amdgcn_mfma_f32_16x16x32_bf16(al, bh3, acc3, 0, 0, 0);

        pa = na; pb = nb;
        bh0 = nh0; bh1 = nh1; bh2 = nh2; bh3 = nh3;
        bl0 = nl0; bl1 = nl1; bl2 = nl2; bl3 = nl3;
    }

    // ---- cross-wave K-reduce via LDS (deterministic fixed order) ----
    __shared__ float red[KSPLIT][64][17];
#pragma unroll
    for (int j = 0; j < 4; ++j) {
        red[wv][lane][ 0 + j] = acc0[j];
        red[wv][lane][ 4 + j] = acc1[j];
        red[wv][lane][ 8 + j] = acc2[j];
        red[wv][lane][12 + j] = acc3[j];
    }
    __syncthreads();
    if (wv != 0) return;

#pragma unroll
    for (int w = 1; w < KSPLIT; ++w)
#pragma unroll
        for (int j = 0; j < 4; ++j) {
            acc0[j] += red[w][lane][ 0 + j];
            acc1[j] += red[w][lane][ 4 + j];
            acc2[j] += red[w][lane][ 8 + j];
            acc3[j] += red[w][lane][12 + j];
        }

    // allowed-expert bitmask (scalar loop, wave 0 only)
    unsigned long long mbits = 0;
    for (int t = 0; t < nids; ++t) {
        const int e = ids[t];
        if (e >= 0 && e < E_NUM) mbits |= (1ull << e);
    }

    // ---- epilogue: mask, logits (f32), softmax + top-8 + renorm ----
    // C/D layout: col = lane&15, row_in_16 = (lane>>4)*4 + reg  (value-verified)
    float* o_log = out;
    float* o_rw  = out + (size_t)T_ROWS * E_NUM;
    float* o_se  = o_rw + (size_t)T_ROWS * TOPK;

#pragma unroll
    for (int j = 0; j < 4; ++j) {
        const int grow = rb + fq * 4 + j;
        float mv0 = ((mbits >> ( 0 + fr)) & 1) ? acc0[j] : -10000.0f;
        float mv1 = ((mbits >> (16 + fr)) & 1) ? acc1[j] : -10000.0f;
        float mv2 = ((mbits >> (32 + fr)) & 1) ? acc2[j] : -10000.0f;
        float mv3 = ((mbits >> (48 + fr)) & 1) ? acc3[j] : -10000.0f;
        o_log[(size_t)grow * 64 +  0 + fr] = mv0;
        o_log[(size_t)grow * 64 + 16 + fr] = mv1;
        o_log[(size_t)grow * 64 + 32 + fr] = mv2;
        o_log[(size_t)grow * 64 + 48 + fr] = mv3;

        float m = fmaxf(fmaxf(mv0, mv1), fmaxf(mv2, mv3));
#pragma unroll
        for (int off = 1; off < 16; off <<= 1) m = fmaxf(m, __shfl_xor(m, off));

        float tsum = 0.f, myv = 0.f;
        int   mye  = 0;
#pragma unroll
        for (int t = 0; t < TOPK; ++t) {
            float bv = mv0; int be = fr;
            if (mv1 > bv) { bv = mv1; be = 16 + fr; }
            if (mv2 > bv) { bv = mv2; be = 32 + fr; }
            if (mv3 > bv) { bv = mv3; be = 48 + fr; }
#pragma unroll
            for (int off = 1; off < 16; off <<= 1) {
                float ov = __shfl_xor(bv, off);
                int   oe = __shfl_xor(be, off);
                if (ov > bv || (ov == bv && oe < be)) { bv = ov; be = oe; }
            }
            const float pv = expf(bv - m);
            tsum += pv;
            if (fr == t) { myv = pv; mye = be; }
            if ((be & 15) == fr) {       // owner lane excludes winner
                const int bn = be >> 4;
                if      (bn == 0) mv0 = -3.4e38f;
                else if (bn == 1) mv1 = -3.4e38f;
                else if (bn == 2) mv2 = -3.4e38f;
                else              mv3 = -3.4e38f;
            }
        }
        if (fr < TOPK) {
            o_rw[(size_t)grow * TOPK + fr] = myv / tsum;
            o_se[(size_t)grow * TOPK + fr] = (float)mye;
        }
    }
}

extern "C" void kernel_launch(void* const* d_in, const int* in_sizes, int n_in,
                              void* d_out, int out_size, void* d_ws, size_t ws_size,
                              hipStream_t stream) {
    const float* X   = (const float*)d_in[0];
    const float* W   = (const float*)d_in[1];
    const int*   ids = (const int*)d_in[2];
    const int    nids = in_sizes[2];
    float* out = (float*)d_out;

    unsigned short* WH = (unsigned short*)d_ws;                       // 512 KB
    unsigned short* WL = WH + (size_t)E_NUM * H_DIM;                  // 512 KB

    hipLaunchKernelGGL(prep_w, dim3(E_NUM * H_DIM / 1024), dim3(256), 0, stream, W, WH, WL);
    hipLaunchKernelGGL(router_main, dim3(T_ROWS / 16), dim3(256), 0, stream,
                       X, WH, WL, ids, nids, out);
}

// Round 6
// 103.929 us; speedup vs baseline: 1.7248x; 1.7248x over previous
//
#include <hip/hip_runtime.h>
#include <hip/hip_bf16.h>

typedef __attribute__((ext_vector_type(4))) float f32x4;
typedef __attribute__((ext_vector_type(8))) short short8v;
typedef __attribute__((ext_vector_type(8))) unsigned short ushort8v;
typedef __attribute__((ext_vector_type(4))) unsigned short ushort4v;

#define T_ROWS 16384
#define H_DIM  4096
#define E_NUM  64
#define TOPK   8
#define MROWS  32               // rows per block
#define KC     128              // k-chunk
#define NCH    (H_DIM / KC)     // 32 chunks

__device__ __forceinline__ unsigned short f2bf(float f) {
    unsigned int u = __float_as_uint(f);
    unsigned int r = (u + 0x7fffu + ((u >> 16) & 1u)) >> 16;  // RNE
    return (unsigned short)r;
}
__device__ __forceinline__ float bf2f(unsigned short h) {
    return __uint_as_float(((unsigned int)h) << 16);
}
// swizzled byte offset inside a [rows][128-ushort] tile (row stride 256 B)
__device__ __forceinline__ int swz(int row, int bytecol) {
    return row * 256 + (bytecol ^ ((row & 7) << 4));
}

// ---- prep: split W f32 [64][4096] into bf16 hi/lo planes in d_ws ----
__global__ __launch_bounds__(256) void prep_w(
    const float* __restrict__ W, unsigned short* __restrict__ WH,
    unsigned short* __restrict__ WL)
{
    const int i = (blockIdx.x * 256 + threadIdx.x) * 4;
    const float4 v = *(const float4*)(W + i);
    float f[4] = {v.x, v.y, v.z, v.w};
    ushort4v h, l;
#pragma unroll
    for (int j = 0; j < 4; ++j) {
        unsigned short hb = f2bf(f[j]);
        h[j] = hb;
        l[j] = f2bf(f[j] - bf2f(hb));
    }
    *(ushort4v*)(WH + i) = h;
    *(ushort4v*)(WL + i) = l;
}

// ---- main: 512 thr = 8 waves; wave (r=w&1, c=w>>1) = 16 rows x 16 experts ----
__global__ __launch_bounds__(512, 4) void router_main(
    const float* __restrict__ X, const unsigned short* __restrict__ WHg,
    const unsigned short* __restrict__ WLg, const int* __restrict__ ids,
    int nids, float* __restrict__ out)
{
    const int tid  = threadIdx.x;
    const int lane = tid & 63;
    const int w    = tid >> 6;        // 0..7
    const int r    = w & 1;           // row-tile
    const int c    = w >> 1;          // expert quarter (16 experts)
    const int rb   = blockIdx.x * MROWS;
    const int fr   = lane & 15;
    const int fq   = lane >> 4;

    __shared__ unsigned short XHs[MROWS * 128];     // 8 KB  (swizzled tiles)
    __shared__ unsigned short XLs[MROWS * 128];     // 8 KB
    __shared__ unsigned short WHs[E_NUM * 128];     // 16 KB
    __shared__ unsigned short WLs[E_NUM * 128];     // 16 KB

    // staging coords
    const int sxrow = tid >> 4;              // 0..31
    const int sxcol = (tid & 15) * 8;        // f32 elems
    const int swrow = tid >> 3;              // 0..63
    const int swcol = (tid & 7) * 16;        // ushorts

    const float*          xg = X   + (size_t)(rb + sxrow) * H_DIM + sxcol;
    const unsigned short* hg = WHg + (size_t)swrow * H_DIM + swcol;
    const unsigned short* lg = WLg + (size_t)swrow * H_DIM + swcol;

    f32x4 acc = {0.f, 0.f, 0.f, 0.f};

    // ---- prefetch chunk 0 into registers ----
    float4 px0 = *(const float4*)(xg);
    float4 px1 = *(const float4*)(xg + 4);
    uint4  ph0 = *(const uint4*)(hg);
    uint4  ph1 = *(const uint4*)(hg + 8);
    uint4  pl0 = *(const uint4*)(lg);
    uint4  pl1 = *(const uint4*)(lg + 8);

    for (int ch = 0; ch < NCH; ++ch) {
        __syncthreads();   // previous chunk's LDS reads done
        // ---- stage: split X regs -> LDS; copy W regs -> LDS (swizzled) ----
        {
            float v[8] = {px0.x, px0.y, px0.z, px0.w, px1.x, px1.y, px1.z, px1.w};
            ushort8v hv, lv;
#pragma unroll
            for (int j = 0; j < 8; ++j) {
                unsigned short hb = f2bf(v[j]);
                hv[j] = hb;
                lv[j] = f2bf(v[j] - bf2f(hb));
            }
            *(ushort8v*)((char*)XHs + swz(sxrow, sxcol * 2)) = hv;
            *(ushort8v*)((char*)XLs + swz(sxrow, sxcol * 2)) = lv;
        }
        *(uint4*)((char*)WHs + swz(swrow, swcol * 2))      = ph0;
        *(uint4*)((char*)WHs + swz(swrow, swcol * 2 + 16)) = ph1;
        *(uint4*)((char*)WLs + swz(swrow, swcol * 2))      = pl0;
        *(uint4*)((char*)WLs + swz(swrow, swcol * 2 + 16)) = pl1;
        __syncthreads();   // tiles ready
        // ---- issue next chunk's global loads (consumed after next barrier) ----
        if (ch + 1 < NCH) {
            const int kb = (ch + 1) * KC;
            px0 = *(const float4*)(xg + kb);
            px1 = *(const float4*)(xg + kb + 4);
            ph0 = *(const uint4*)(hg + kb);
            ph1 = *(const uint4*)(hg + kb + 8);
            pl0 = *(const uint4*)(lg + kb);
            pl1 = *(const uint4*)(lg + kb + 8);
        }
        // ---- compute: 4 k-steps x 3 MFMA (split-bf16) from swizzled LDS ----
#pragma unroll
        for (int ks = 0; ks < KC / 32; ++ks) {
            const int bc = ks * 64 + fq * 16;
            short8v ah = *(const short8v*)((const char*)XHs + swz(r * 16 + fr, bc));
            short8v al = *(const short8v*)((const char*)XLs + swz(r * 16 + fr, bc));
            short8v bh = *(const short8v*)((const char*)WHs + swz(c * 16 + fr, bc));
            short8v bl = *(const short8v*)((const char*)WLs + swz(c * 16 + fr, bc));
            acc = __builtin_amdgcn_mfma_f32_16x16x32_bf16(ah, bh, acc, 0, 0, 0);
            acc = __builtin_amdgcn_mfma_f32_16x16x32_bf16(ah, bl, acc, 0, 0, 0);
            acc = __builtin_amdgcn_mfma_f32_16x16x32_bf16(al, bh, acc, 0, 0, 0);
        }
    }

    // ---- logits scoreboard in LDS (reuse X-tile space), then epilogue ----
    __syncthreads();                       // all compute (LDS reads) done
    float* sm = (float*)XHs;               // [MROWS][68] padded, 8.7 KB <= 16 KB
#pragma unroll
    for (int j = 0; j < 4; ++j) {
        const int row_l = r * 16 + fq * 4 + j;
        sm[row_l * 68 + c * 16 + fr] = acc[j];
    }
    __syncthreads();
    if (w >= 2) return;                    // no barriers after this point

    // allowed-expert bitmask (uniform; scalar-cached)
    unsigned long long mbits = 0;
    for (int t = 0; t < nids; ++t) {
        const int e = ids[t];
        if (e >= 0 && e < E_NUM) mbits |= (1ull << e);
    }

    float* o_log = out;
    float* o_rw  = out + (size_t)T_ROWS * E_NUM;
    float* o_se  = o_rw + (size_t)T_ROWS * TOPK;

    // wave w (=r) handles rows r*16..r*16+15 with the value-verified epilogue.
#pragma unroll
    for (int j = 0; j < 4; ++j) {
        const int row_l = r * 16 + fq * 4 + j;
        const int grow  = rb + row_l;
        float a0 = sm[row_l * 68 +  0 + fr];
        float a1 = sm[row_l * 68 + 16 + fr];
        float a2 = sm[row_l * 68 + 32 + fr];
        float a3 = sm[row_l * 68 + 48 + fr];
        float mv0 = ((mbits >> ( 0 + fr)) & 1) ? a0 : -10000.0f;
        float mv1 = ((mbits >> (16 + fr)) & 1) ? a1 : -10000.0f;
        float mv2 = ((mbits >> (32 + fr)) & 1) ? a2 : -10000.0f;
        float mv3 = ((mbits >> (48 + fr)) & 1) ? a3 : -10000.0f;
        o_log[(size_t)grow * 64 +  0 + fr] = mv0;
        o_log[(size_t)grow * 64 + 16 + fr] = mv1;
        o_log[(size_t)grow * 64 + 32 + fr] = mv2;
        o_log[(size_t)grow * 64 + 48 + fr] = mv3;

        float m = fmaxf(fmaxf(mv0, mv1), fmaxf(mv2, mv3));
#pragma unroll
        for (int off = 1; off < 16; off <<= 1) m = fmaxf(m, __shfl_xor(m, off));

        float tsum = 0.f, myv = 0.f;
        int   mye  = 0;
#pragma unroll
        for (int t = 0; t < TOPK; ++t) {
            float bv = mv0; int be = fr;
            if (mv1 > bv) { bv = mv1; be = 16 + fr; }
            if (mv2 > bv) { bv = mv2; be = 32 + fr; }
            if (mv3 > bv) { bv = mv3; be = 48 + fr; }
#pragma unroll
            for (int off = 1; off < 16; off <<= 1) {
                float ov = __shfl_xor(bv, off);
                int   oe = __shfl_xor(be, off);
                if (ov > bv || (ov == bv && oe < be)) { bv = ov; be = oe; }
            }
            const float pv = expf(bv - m);
            tsum += pv;
            if (fr == t) { myv = pv; mye = be; }
            if ((be & 15) == fr) {       // owner lane excludes winner
                const int bn = be >> 4;
                if      (bn == 0) mv0 = -3.4e38f;
                else if (bn == 1) mv1 = -3.4e38f;
                else if (bn == 2) mv2 = -3.4e38f;
                else              mv3 = -3.4e38f;
            }
        }
        if (fr < TOPK) {
            o_rw[(size_t)grow * TOPK + fr] = myv / tsum;
            o_se[(size_t)grow * TOPK + fr] = (float)mye;
        }
    }
}

extern "C" void kernel_launch(void* const* d_in, const int* in_sizes, int n_in,
                              void* d_out, int out_size, void* d_ws, size_t ws_size,
                              hipStream_t stream) {
    const float* X   = (const float*)d_in[0];
    const float* W   = (const float*)d_in[1];
    const int*   ids = (const int*)d_in[2];
    const int    nids = in_sizes[2];
    float* out = (float*)d_out;

    unsigned short* WH = (unsigned short*)d_ws;                   // 512 KB
    unsigned short* WL = WH + (size_t)E_NUM * H_DIM;              // 512 KB

    hipLaunchKernelGGL(prep_w, dim3(E_NUM * H_DIM / 1024), dim3(256), 0, stream, W, WH, WL);
    hipLaunchKernelGGL(router_main, dim3(T_ROWS / MROWS), dim3(512), 0, stream,
                       X, WH, WL, ids, nids, out);
}